// Round 1
// baseline (1506.948 us; speedup 1.0000x reference)
//
#include <hip/hip_runtime.h>
#include <math.h>

#define Bn 128
#define Tn 32
#define Hn 768
#define En 4
#define Fn 3072
#define Rn 256            // NUM_BEAMS * B

#define FC 256            // F-chunk
#define NCH (Fn/FC)       // 12
#define XSTRIDE 36        // padded [h][t] row (36*4=144B, 16B-aligned)

static constexpr size_t OUT_ELEMS  = (size_t)Rn*Tn*Hn;       // 6291456
static constexpr size_t SCORES_OFF = OUT_ELEMS;
static constexpr size_t ROUTE_OFF  = OUT_ELEMS + Rn;
static constexpr size_t BIDX_OFF   = OUT_ELEMS + 2*Rn;
static constexpr size_t LOSS_OFF   = OUT_ELEMS + 3*Rn;

// ws layout: float prob_gate[128*4] | float score[256] | int route[256]

__global__ __launch_bounds__(64) void gate_kernel(
    const float* __restrict__ x, const float* __restrict__ Wg,
    float* __restrict__ out, float* __restrict__ wsf, int* __restrict__ wsi)
{
  const int b = blockIdx.x;
  const int l = threadIdx.x;
  float acc0=0.f, acc1=0.f, acc2=0.f, acc3=0.f;
  const float* xb = x + (size_t)b*Tn*Hn;
  for (int h = l; h < Hn; h += 64) {
    float xa = 0.f;
    #pragma unroll
    for (int t = 0; t < Tn; ++t) xa += xb[t*Hn + h];
    xa *= (1.0f/Tn);
    acc0 += xa * Wg[0*Hn + h];
    acc1 += xa * Wg[1*Hn + h];
    acc2 += xa * Wg[2*Hn + h];
    acc3 += xa * Wg[3*Hn + h];
  }
  #pragma unroll
  for (int o = 32; o > 0; o >>= 1) {
    acc0 += __shfl_down(acc0, o);
    acc1 += __shfl_down(acc1, o);
    acc2 += __shfl_down(acc2, o);
    acc3 += __shfl_down(acc3, o);
  }
  if (l == 0) {
    float lg[4] = {acc0, acc1, acc2, acc3};
    float m = fmaxf(fmaxf(lg[0],lg[1]), fmaxf(lg[2],lg[3]));
    float p[4]; float s = 0.f;
    #pragma unroll
    for (int e = 0; e < 4; ++e) { p[e] = expf(lg[e]-m); s += p[e]; }
    float inv = 1.f/s;
    #pragma unroll
    for (int e = 0; e < 4; ++e) { p[e] *= inv; wsf[b*4+e] = p[e]; }
    // top-2, ties -> lower index (matches jax.lax.top_k)
    int i1 = 0;
    #pragma unroll
    for (int e = 1; e < 4; ++e) if (p[e] > p[i1]) i1 = e;
    int i2 = (i1 == 0) ? 1 : 0;
    #pragma unroll
    for (int e = 0; e < 4; ++e) if (e != i1 && p[e] > p[i2]) i2 = e;
    int idx[2] = {i1, i2};
    #pragma unroll
    for (int k = 0; k < 2; ++k) {
      int r = 2*b + k;
      float pv = p[idx[k]];
      wsf[512 + r] = pv;
      wsi[r] = idx[k];
      out[SCORES_OFF + r] = pv;
      out[ROUTE_OFF  + r] = (float)idx[k];
      out[BIDX_OFF   + r] = (float)r;
    }
  }
}

__global__ __launch_bounds__(64) void loss_kernel(
    const float* __restrict__ wsf, float* __restrict__ out)
{
  const int l = threadIdx.x;
  float i0=0.f,i1=0.f,i2=0.f,i3=0.f;
  for (int b = l; b < Bn; b += 64) {
    i0 += wsf[b*4+0]; i1 += wsf[b*4+1]; i2 += wsf[b*4+2]; i3 += wsf[b*4+3];
  }
  #pragma unroll
  for (int o = 32; o > 0; o >>= 1) {
    i0 += __shfl_down(i0,o); i1 += __shfl_down(i1,o);
    i2 += __shfl_down(i2,o); i3 += __shfl_down(i3,o);
  }
  if (l == 0) {
    float mean = 0.25f*(i0+i1+i2+i3);
    float d0=i0-mean, d1=i1-mean, d2=i2-mean, d3=i3-mean;
    float var = (d0*d0+d1*d1+d2*d2+d3*d3) * (1.f/3.f);  // ddof=1
    out[LOSS_OFF] = var / (mean*mean);
  }
}

// One block per beam. Fused: h1 = gelu(x@W1[e]+b1[e]) chunk-wise in LDS,
// out accumulated in registers (24/thread), scaled by gate score.
__global__ __launch_bounds__(1024, 4) void mlp_kernel(
    const float* __restrict__ x,
    const float* __restrict__ W1, const float* __restrict__ b1,
    const float* __restrict__ W2, const float* __restrict__ b2,
    const float* __restrict__ wsf, const int* __restrict__ wsi,
    float* __restrict__ out)
{
  extern __shared__ __align__(16) float sm[];
  float* xs = sm;                    // [Hn][XSTRIDE]  (x transposed, [h][t])
  float* h1 = sm + Hn*XSTRIDE;       // [FC][Tn]
  const int r  = blockIdx.x;
  const int bb = r >> 1;
  const int e  = wsi[r];
  const float sc = wsf[512 + r];
  const int tid = threadIdx.x;

  // stage x[b] -> xs[h][t]   (coalesced global read; 8-way LDS write conflict, one-time)
  const float* xp = x + (size_t)bb*Tn*Hn;
  for (int i = tid; i < Tn*Hn; i += 1024) {
    int t = i / Hn;
    int h = i - t*Hn;
    xs[h*XSTRIDE + t] = xp[i];
  }

  const int fcol = tid & 255;        // f within chunk / h-column in phase B
  const int tq   = tid >> 8;         // 0..3
  const int t0   = tq * 8;           // 8 t-rows per thread

  float oacc[8][3];
  #pragma unroll
  for (int i=0;i<8;++i)
    #pragma unroll
    for (int j=0;j<3;++j) oacc[i][j]=0.f;

  const float* w1col = W1 + (size_t)e*Hn*Fn + fcol;
  const float* b1e   = b1 + e*Fn;
  const float* w2e   = W2 + (size_t)e*Fn*Hn;

  for (int c = 0; c < NCH; ++c) {
    const int fb = c * FC;
    __syncthreads();   // prev phase B done reading h1 / staging done
    // ---- Phase A: h1[fcol][t0..t0+7] = gelu(x @ W1col + b1) ----
    float a[8];
    #pragma unroll
    for (int i=0;i<8;++i) a[i]=0.f;
    const float* w1p = w1col + fb;
    #pragma unroll 4
    for (int h = 0; h < Hn; ++h) {
      float w = w1p[(size_t)h*Fn];
      const float4 xa = *(const float4*)(xs + h*XSTRIDE + t0);
      const float4 xb2 = *(const float4*)(xs + h*XSTRIDE + t0 + 4);
      a[0] += xa.x*w;  a[1] += xa.y*w;  a[2] += xa.z*w;  a[3] += xa.w*w;
      a[4] += xb2.x*w; a[5] += xb2.y*w; a[6] += xb2.z*w; a[7] += xb2.w*w;
    }
    const float bv = b1e[fb + fcol];
    float g[8];
    #pragma unroll
    for (int i=0;i<8;++i) {
      float z = a[i] + bv;
      g[i] = 0.5f*z*(1.f + erff(z*0.70710678118f));   // exact gelu
    }
    *(float4*)(h1 + fcol*Tn + t0)     = make_float4(g[0],g[1],g[2],g[3]);
    *(float4*)(h1 + fcol*Tn + t0 + 4) = make_float4(g[4],g[5],g[6],g[7]);
    __syncthreads();
    // ---- Phase B: oacc += h1_chunk @ W2_chunk ----
    const float* w2p = w2e + (size_t)fb*Hn;
    #pragma unroll 2
    for (int f = 0; f < FC; ++f) {
      const float w0  = w2p[f*Hn + fcol];
      const float wv1 = w2p[f*Hn + fcol + 256];
      const float wv2 = w2p[f*Hn + fcol + 512];
      const float4 ha = *(const float4*)(h1 + f*Tn + t0);
      const float4 hb = *(const float4*)(h1 + f*Tn + t0 + 4);
      float hv[8] = {ha.x,ha.y,ha.z,ha.w,hb.x,hb.y,hb.z,hb.w};
      #pragma unroll
      for (int i=0;i<8;++i) {
        oacc[i][0] += hv[i]*w0;
        oacc[i][1] += hv[i]*wv1;
        oacc[i][2] += hv[i]*wv2;
      }
    }
  }

  // epilogue: out[r,t,h] = sc * (acc + b2)
  const float* b2e = b2 + e*Hn;
  float* op = out + (size_t)r*Tn*Hn;
  #pragma unroll
  for (int i=0;i<8;++i) {
    #pragma unroll
    for (int j=0;j<3;++j) {
      int h = fcol + 256*j;
      op[(t0+i)*Hn + h] = sc * (oacc[i][j] + b2e[h]);
    }
  }
}

extern "C" void kernel_launch(void* const* d_in, const int* in_sizes, int n_in,
                              void* d_out, int out_size, void* d_ws, size_t ws_size,
                              hipStream_t stream)
{
  const float* x  = (const float*)d_in[0];
  const float* Wg = (const float*)d_in[1];
  const float* W1 = (const float*)d_in[2];
  const float* b1 = (const float*)d_in[3];
  const float* W2 = (const float*)d_in[4];
  const float* b2 = (const float*)d_in[5];
  float* out = (float*)d_out;
  float* wsf = (float*)d_ws;
  int*   wsi = (int*)((float*)d_ws + 768);

  gate_kernel<<<Bn, 64, 0, stream>>>(x, Wg, out, wsf, wsi);
  loss_kernel<<<1, 64, 0, stream>>>(wsf, out);

  size_t smem = (size_t)(Hn*XSTRIDE + FC*Tn) * sizeof(float);  // 143360 B
  hipFuncSetAttribute((const void*)mlp_kernel,
                      hipFuncAttributeMaxDynamicSharedMemorySize, (int)smem);
  mlp_kernel<<<Rn, 1024, smem, stream>>>(x, W1, b1, W2, b2, wsf, wsi, out);
}

// Round 2
// 463.726 us; speedup vs baseline: 3.2497x; 3.2497x over previous
//
#include <hip/hip_runtime.h>
#include <math.h>

typedef _Float16 f16;
typedef _Float16 f16x8 __attribute__((ext_vector_type(8)));
typedef float f32x4 __attribute__((ext_vector_type(4)));

#define Bn 128
#define Tn 32
#define Hn 768
#define En 4
#define Fn 3072
#define Rn 256

static constexpr size_t OUT_ELEMS  = (size_t)Rn*Tn*Hn;
static constexpr size_t SCORES_OFF = OUT_ELEMS;
static constexpr size_t ROUTE_OFF  = OUT_ELEMS + Rn;
static constexpr size_t BIDX_OFF   = OUT_ELEMS + 2*Rn;
static constexpr size_t LOSS_OFF   = OUT_ELEMS + 3*Rn;

// ws byte offsets
#define WS_WSF    0u
#define WS_ROUTE  4096u
#define WS_GRP    8192u
#define WS_X16    16384u
#define WS_W1T    (WS_X16 + 2u*Bn*Tn*Hn)        // + 6291456
#define WS_W2T    (WS_W1T + 2u*En*Hn*Fn)        // + 18874368
#define WS_H1     (WS_W2T + 2u*En*Fn*Hn)        // + 18874368   (h1: 50331648 B)

__global__ __launch_bounds__(64) void gate_kernel(
    const float* __restrict__ x, const float* __restrict__ Wg,
    float* __restrict__ out, float* __restrict__ wsf, int* __restrict__ route)
{
  const int b = blockIdx.x;
  const int l = threadIdx.x;
  float acc0=0.f, acc1=0.f, acc2=0.f, acc3=0.f;
  const float* xb = x + (size_t)b*Tn*Hn;
  for (int h = l; h < Hn; h += 64) {
    float xa = 0.f;
    #pragma unroll
    for (int t = 0; t < Tn; ++t) xa += xb[t*Hn + h];
    xa *= (1.0f/Tn);
    acc0 += xa * Wg[0*Hn + h];
    acc1 += xa * Wg[1*Hn + h];
    acc2 += xa * Wg[2*Hn + h];
    acc3 += xa * Wg[3*Hn + h];
  }
  #pragma unroll
  for (int o = 32; o > 0; o >>= 1) {
    acc0 += __shfl_down(acc0, o);
    acc1 += __shfl_down(acc1, o);
    acc2 += __shfl_down(acc2, o);
    acc3 += __shfl_down(acc3, o);
  }
  if (l == 0) {
    float lg[4] = {acc0, acc1, acc2, acc3};
    float m = fmaxf(fmaxf(lg[0],lg[1]), fmaxf(lg[2],lg[3]));
    float p[4]; float s = 0.f;
    #pragma unroll
    for (int e = 0; e < 4; ++e) { p[e] = expf(lg[e]-m); s += p[e]; }
    float inv = 1.f/s;
    #pragma unroll
    for (int e = 0; e < 4; ++e) { p[e] *= inv; wsf[b*4+e] = p[e]; }
    int i1 = 0;
    #pragma unroll
    for (int e = 1; e < 4; ++e) if (p[e] > p[i1]) i1 = e;
    int i2 = (i1 == 0) ? 1 : 0;
    #pragma unroll
    for (int e = 0; e < 4; ++e) if (e != i1 && p[e] > p[i2]) i2 = e;
    int idx[2] = {i1, i2};
    #pragma unroll
    for (int k = 0; k < 2; ++k) {
      int r = 2*b + k;
      float pv = p[idx[k]];
      wsf[512 + r] = pv;
      route[r] = idx[k];
      out[SCORES_OFF + r] = pv;
      out[ROUTE_OFF  + r] = (float)idx[k];
      out[BIDX_OFF   + r] = (float)r;
    }
  }
}

__global__ __launch_bounds__(64) void loss_kernel(
    const float* __restrict__ wsf, float* __restrict__ out)
{
  const int l = threadIdx.x;
  float i0=0.f,i1=0.f,i2=0.f,i3=0.f;
  for (int b = l; b < Bn; b += 64) {
    i0 += wsf[b*4+0]; i1 += wsf[b*4+1]; i2 += wsf[b*4+2]; i3 += wsf[b*4+3];
  }
  #pragma unroll
  for (int o = 32; o > 0; o >>= 1) {
    i0 += __shfl_down(i0,o); i1 += __shfl_down(i1,o);
    i2 += __shfl_down(i2,o); i3 += __shfl_down(i3,o);
  }
  if (l == 0) {
    float mean = 0.25f*(i0+i1+i2+i3);
    float d0=i0-mean, d1=i1-mean, d2=i2-mean, d3=i3-mean;
    float var = (d0*d0+d1*d1+d2*d2+d3*d3) * (1.f/3.f);
    out[LOSS_OFF] = var / (mean*mean);
  }
}

// grp layout (ints): [0]=ntiles; tiles at [8+3i] = {e, bstart, nbeams}; blist at [128..383]
__global__ __launch_bounds__(64) void group_kernel(
    const int* __restrict__ route, int* __restrict__ grp)
{
  const int l = threadIdx.x;
  int cnt = 0;
  if (l < 4) { for (int r = 0; r < Rn; ++r) cnt += (route[r] == l); }
  int c0 = __shfl(cnt, 0), c1 = __shfl(cnt, 1), c2 = __shfl(cnt, 2), c3 = __shfl(cnt, 3);
  int off = (l >= 1 ? c0 : 0) + (l >= 2 ? c1 : 0) + (l >= 3 ? c2 : 0);
  if (l < 4) {
    int p = off;
    for (int r = 0; r < Rn; ++r) if (route[r] == l) grp[128 + p++] = r;
  }
  if (l == 0) {
    int cs[4] = {c0, c1, c2, c3};
    int os[4] = {0, c0, c0+c1, c0+c1+c2};
    int nt = 0;
    for (int e = 0; e < 4; ++e) {
      for (int s = 0; s < cs[e]; s += 8) {
        int nb = cs[e] - s; if (nb > 8) nb = 8;
        grp[8+nt*3+0] = e; grp[8+nt*3+1] = os[e]+s; grp[8+nt*3+2] = nb;
        ++nt;
      }
    }
    grp[0] = nt;
  }
}

__global__ __launch_bounds__(256) void convx_kernel(
    const float* __restrict__ x, f16* __restrict__ x16)
{
  const int i = (blockIdx.x*256 + threadIdx.x) * 8;
  float4 a = *(const float4*)(x + i);
  float4 b = *(const float4*)(x + i + 4);
  union { f16 h[8]; uint4 u; } p;
  p.h[0]=(f16)a.x; p.h[1]=(f16)a.y; p.h[2]=(f16)a.z; p.h[3]=(f16)a.w;
  p.h[4]=(f16)b.x; p.h[5]=(f16)b.y; p.h[6]=(f16)b.z; p.h[7]=(f16)b.w;
  *(uint4*)(x16 + i) = p.u;
}

// src [E][R][C] fp32 -> dst [E][C][R] fp16.  grid (C/64, R/64, E), block 256.
__global__ __launch_bounds__(256) void transcvt_kernel(
    const float* __restrict__ src, f16* __restrict__ dst, int R, int C)
{
  __shared__ f16 t[64][74];
  const int e  = blockIdx.z;
  const int r0 = blockIdx.y*64, c0 = blockIdx.x*64;
  const float* s = src + (size_t)e*R*C;
  f16* d = dst + (size_t)e*R*C;
  const int tid = threadIdx.x;
  const int i  = tid >> 2;         // 0..63
  const int j0 = (tid & 3) * 16;
  #pragma unroll
  for (int q = 0; q < 16; q += 4) {
    float4 v = *(const float4*)(s + (size_t)(r0+i)*C + c0 + j0 + q);
    t[i][j0+q+0]=(f16)v.x; t[i][j0+q+1]=(f16)v.y; t[i][j0+q+2]=(f16)v.z; t[i][j0+q+3]=(f16)v.w;
  }
  __syncthreads();
  f16 o[16];
  #pragma unroll
  for (int q = 0; q < 16; ++q) o[q] = t[j0+q][i];
  *(uint4*)(d + (size_t)(c0+i)*R + r0 + j0)     = *(uint4*)&o[0];
  *(uint4*)(d + (size_t)(c0+i)*R + r0 + j0 + 8) = *(uint4*)&o[8];
}

// Grouped GEMM: C[256 x BN] = act(A @ B^T + bias), rows gathered per beam list.
// A16: [.][KD] row-major fp16; B16: [E][ND][KD] fp16 (pre-transposed).
// G1: out = gelu -> oh (fp16, [r*32+t][ND]); G2: out = score*(v+bias) -> of (fp32).
template<int KD, int ND, int BN, int MI, int NI, int WGN, bool G1>
__global__ __launch_bounds__(512, 2) void gemm_kernel(
    const f16* __restrict__ A16, const f16* __restrict__ B16,
    const float* __restrict__ bias, f16* __restrict__ oh,
    float* __restrict__ of, const int* __restrict__ grp,
    const float* __restrict__ wsf)
{
  const int ntiles = grp[0];
  const int tix = blockIdx.x;
  if (tix >= ntiles) return;
  const int e      = grp[8+tix*3+0];
  const int bstart = grp[8+tix*3+1];
  const int nb     = grp[8+tix*3+2];
  const int n0     = blockIdx.y * BN;
  const int tid    = threadIdx.x;

  extern __shared__ char smem[];
  f16 (*As)[72] = (f16(*)[72])smem;
  f16 (*Bs)[72] = (f16(*)[72])(smem + 256*72*2);
  int* rbeam = (int*)(smem + 256*72*2 + (size_t)BN*72*2);

  if (tid < 256) {
    int s = tid >> 5; if (s >= nb) s = nb - 1;
    rbeam[tid] = grp[128 + bstart + s];
  }

  // A staging: thread -> row tid>>1, k-half (tid&1)*32  (4x uint4 = 32 fp16)
  const int arow = tid >> 1;
  const int akb  = (tid & 1) * 32;
  int aslot = arow >> 5; if (aslot >= nb) aslot = nb - 1;
  const int ar = grp[128 + bstart + aslot];
  const size_t arowbase = G1 ? ((size_t)(ar>>1)*Tn + (arow&31)) * (size_t)KD
                             : ((size_t)ar*Tn + (arow&31)) * (size_t)KD;
  const f16* aptr = A16 + arowbase + akb;

  constexpr int BNC = BN/64;          // uint4 loads per thread for B (4 or 2)
  const int brow = (BNC==4) ? (tid>>1) : (tid>>2);
  const int bkb  = (BNC==4) ? (tid&1)*32 : (tid&3)*16;
  const f16* bptr = B16 + (size_t)e*ND*KD + (size_t)(n0+brow)*KD + bkb;

  const int lane = tid & 63;
  const int w    = tid >> 6;
  const int wm   = w / WGN;
  const int wn   = w % WGN;
  const int lr   = lane & 15;
  const int lk   = lane >> 4;
  const int rowA0 = wm*(MI*16);
  const int rowB0 = wn*(NI*16);

  f32x4 acc[MI][NI];
  #pragma unroll
  for (int i=0;i<MI;++i)
    #pragma unroll
    for (int j=0;j<NI;++j) acc[i][j] = (f32x4){0.f,0.f,0.f,0.f};

  uint4 av[4], bv[BNC];
  #pragma unroll
  for (int q=0;q<4;++q) av[q] = *(const uint4*)(aptr + q*8);
  #pragma unroll
  for (int q=0;q<BNC;++q) bv[q] = *(const uint4*)(bptr + q*8);

  constexpr int NT = KD/64;
  for (int kt = 0; kt < NT; ++kt) {
    __syncthreads();
    #pragma unroll
    for (int q=0;q<4;++q) *(uint4*)&As[arow][akb + q*8] = av[q];
    #pragma unroll
    for (int q=0;q<BNC;++q) *(uint4*)&Bs[brow][bkb + q*8] = bv[q];
    __syncthreads();
    if (kt + 1 < NT) {
      const f16* ap = aptr + (size_t)(kt+1)*64;
      const f16* bp = bptr + (size_t)(kt+1)*64;
      #pragma unroll
      for (int q=0;q<4;++q) av[q] = *(const uint4*)(ap + q*8);
      #pragma unroll
      for (int q=0;q<BNC;++q) bv[q] = *(const uint4*)(bp + q*8);
    }
    #pragma unroll
    for (int ks = 0; ks < 2; ++ks) {
      f16x8 af[MI], bf[NI];
      #pragma unroll
      for (int mi=0;mi<MI;++mi)
        af[mi] = *(const f16x8*)&As[rowA0 + mi*16 + lr][ks*32 + lk*8];
      #pragma unroll
      for (int ni=0;ni<NI;++ni)
        bf[ni] = *(const f16x8*)&Bs[rowB0 + ni*16 + lr][ks*32 + lk*8];
      #pragma unroll
      for (int mi=0;mi<MI;++mi)
        #pragma unroll
        for (int ni=0;ni<NI;++ni)
          acc[mi][ni] = __builtin_amdgcn_mfma_f32_16x16x32_f16(af[mi], bf[ni], acc[mi][ni], 0, 0, 0);
    }
  }

  const int nvalid = nb * Tn;
  float bvals[NI];
  #pragma unroll
  for (int ni=0;ni<NI;++ni) bvals[ni] = bias[e*ND + n0 + rowB0 + ni*16 + lr];

  #pragma unroll
  for (int mi=0;mi<MI;++mi){
    #pragma unroll
    for (int j=0;j<4;++j){
      const int m = rowA0 + mi*16 + (lane>>4)*4 + j;
      if (m >= nvalid) continue;
      const int r = rbeam[m];
      const int t = m & 31;
      if (G1) {
        f16* orow = oh + ((size_t)r*Tn + t)*(size_t)ND + n0;
        #pragma unroll
        for (int ni=0;ni<NI;++ni){
          float v = acc[mi][ni][j] + bvals[ni];
          float g = 0.5f*v*(1.f + erff(v*0.70710678118f));
          orow[rowB0 + ni*16 + lr] = (f16)g;
        }
      } else {
        const float sc = wsf[512 + r];
        float* orow = of + ((size_t)r*Tn + t)*(size_t)Hn + n0;
        #pragma unroll
        for (int ni=0;ni<NI;++ni){
          float v = acc[mi][ni][j] + bvals[ni];
          orow[rowB0 + ni*16 + lr] = sc * v;
        }
      }
    }
  }
}

extern "C" void kernel_launch(void* const* d_in, const int* in_sizes, int n_in,
                              void* d_out, int out_size, void* d_ws, size_t ws_size,
                              hipStream_t stream)
{
  const float* x  = (const float*)d_in[0];
  const float* Wg = (const float*)d_in[1];
  const float* W1 = (const float*)d_in[2];
  const float* b1 = (const float*)d_in[3];
  const float* W2 = (const float*)d_in[4];
  const float* b2 = (const float*)d_in[5];
  float* out = (float*)d_out;
  char* ws = (char*)d_ws;
  float* wsf  = (float*)(ws + WS_WSF);
  int*   route= (int*)(ws + WS_ROUTE);
  int*   grp  = (int*)(ws + WS_GRP);
  f16*   x16  = (f16*)(ws + WS_X16);
  f16*   w1t  = (f16*)(ws + WS_W1T);
  f16*   w2t  = (f16*)(ws + WS_W2T);
  f16*   h1   = (f16*)(ws + WS_H1);

  gate_kernel<<<Bn, 64, 0, stream>>>(x, Wg, out, wsf, route);
  group_kernel<<<1, 64, 0, stream>>>(route, grp);
  loss_kernel<<<1, 64, 0, stream>>>(wsf, out);
  convx_kernel<<<1536, 256, 0, stream>>>(x, x16);
  transcvt_kernel<<<dim3(48,12,4), 256, 0, stream>>>(W1, w1t, Hn, Fn);
  transcvt_kernel<<<dim3(12,48,4), 256, 0, stream>>>(W2, w2t, Fn, Hn);

  auto g1 = gemm_kernel<Hn, Fn, 256, 8, 4, 4, true>;
  auto g2 = gemm_kernel<Fn, Hn, 128, 4, 4, 2, false>;
  const int sm1 = 256*72*2 + 256*72*2 + 256*4;   // 74752 B
  const int sm2 = 256*72*2 + 128*72*2 + 256*4;   // 56320 B
  hipFuncSetAttribute((const void*)g1, hipFuncAttributeMaxDynamicSharedMemorySize, sm1);
  hipFuncSetAttribute((const void*)g2, hipFuncAttributeMaxDynamicSharedMemorySize, sm2);
  g1<<<dim3(35,12), 512, sm1, stream>>>(x16, w1t, b1, h1, nullptr, grp, wsf);
  g2<<<dim3(35,6),  512, sm2, stream>>>(h1, w2t, b2, nullptr, out, grp, wsf);
}

// Round 3
// 377.138 us; speedup vs baseline: 3.9958x; 1.2296x over previous
//
#include <hip/hip_runtime.h>
#include <math.h>

typedef _Float16 f16;
typedef _Float16 f16x8 __attribute__((ext_vector_type(8)));
typedef float f32x4 __attribute__((ext_vector_type(4)));

#define Bn 128
#define Tn 32
#define Hn 768
#define En 4
#define Fn 3072
#define Rn 256

static constexpr size_t OUT_ELEMS  = (size_t)Rn*Tn*Hn;
static constexpr size_t SCORES_OFF = OUT_ELEMS;
static constexpr size_t ROUTE_OFF  = OUT_ELEMS + Rn;
static constexpr size_t BIDX_OFF   = OUT_ELEMS + 2*Rn;
static constexpr size_t LOSS_OFF   = OUT_ELEMS + 3*Rn;

// ws byte offsets
#define WS_WSF    0u
#define WS_ROUTE  4096u
#define WS_GRP    8192u
#define WS_X16    16384u
#define WS_W1T    (WS_X16 + 2u*Bn*Tn*Hn)
#define WS_W2T    (WS_W1T + 2u*En*Hn*Fn)
#define WS_H1     (WS_W2T + 2u*En*Fn*Hn)

__global__ __launch_bounds__(64) void gate_kernel(
    const float* __restrict__ x, const float* __restrict__ Wg,
    float* __restrict__ out, float* __restrict__ wsf, int* __restrict__ route)
{
  const int b = blockIdx.x;
  const int l = threadIdx.x;
  float acc0=0.f, acc1=0.f, acc2=0.f, acc3=0.f;
  const float* xb = x + (size_t)b*Tn*Hn;
  for (int h = l; h < Hn; h += 64) {
    float xa = 0.f;
    #pragma unroll
    for (int t = 0; t < Tn; ++t) xa += xb[t*Hn + h];
    xa *= (1.0f/Tn);
    acc0 += xa * Wg[0*Hn + h];
    acc1 += xa * Wg[1*Hn + h];
    acc2 += xa * Wg[2*Hn + h];
    acc3 += xa * Wg[3*Hn + h];
  }
  #pragma unroll
  for (int o = 32; o > 0; o >>= 1) {
    acc0 += __shfl_down(acc0, o);
    acc1 += __shfl_down(acc1, o);
    acc2 += __shfl_down(acc2, o);
    acc3 += __shfl_down(acc3, o);
  }
  if (l == 0) {
    float lg[4] = {acc0, acc1, acc2, acc3};
    float m = fmaxf(fmaxf(lg[0],lg[1]), fmaxf(lg[2],lg[3]));
    float p[4]; float s = 0.f;
    #pragma unroll
    for (int e = 0; e < 4; ++e) { p[e] = expf(lg[e]-m); s += p[e]; }
    float inv = 1.f/s;
    #pragma unroll
    for (int e = 0; e < 4; ++e) { p[e] *= inv; wsf[b*4+e] = p[e]; }
    int i1 = 0;
    #pragma unroll
    for (int e = 1; e < 4; ++e) if (p[e] > p[i1]) i1 = e;
    int i2 = (i1 == 0) ? 1 : 0;
    #pragma unroll
    for (int e = 0; e < 4; ++e) if (e != i1 && p[e] > p[i2]) i2 = e;
    int idx[2] = {i1, i2};
    #pragma unroll
    for (int k = 0; k < 2; ++k) {
      int r = 2*b + k;
      float pv = p[idx[k]];
      wsf[512 + r] = pv;
      route[r] = idx[k];
      out[SCORES_OFF + r] = pv;
      out[ROUTE_OFF  + r] = (float)idx[k];
      out[BIDX_OFF   + r] = (float)r;
    }
  }
}

__global__ __launch_bounds__(64) void loss_kernel(
    const float* __restrict__ wsf, float* __restrict__ out)
{
  const int l = threadIdx.x;
  float i0=0.f,i1=0.f,i2=0.f,i3=0.f;
  for (int b = l; b < Bn; b += 64) {
    i0 += wsf[b*4+0]; i1 += wsf[b*4+1]; i2 += wsf[b*4+2]; i3 += wsf[b*4+3];
  }
  #pragma unroll
  for (int o = 32; o > 0; o >>= 1) {
    i0 += __shfl_down(i0,o); i1 += __shfl_down(i1,o);
    i2 += __shfl_down(i2,o); i3 += __shfl_down(i3,o);
  }
  if (l == 0) {
    float mean = 0.25f*(i0+i1+i2+i3);
    float d0=i0-mean, d1=i1-mean, d2=i2-mean, d3=i3-mean;
    float var = (d0*d0+d1*d1+d2*d2+d3*d3) * (1.f/3.f);
    out[LOSS_OFF] = var / (mean*mean);
  }
}

// grp layout (ints): [0]=ntiles; tiles at [8+3i] = {e, bstart, nbeams}; blist at [128..383]
__global__ __launch_bounds__(64) void group_kernel(
    const int* __restrict__ route, int* __restrict__ grp)
{
  const int l = threadIdx.x;
  int cnt = 0;
  if (l < 4) { for (int r = 0; r < Rn; ++r) cnt += (route[r] == l); }
  int c0 = __shfl(cnt, 0), c1 = __shfl(cnt, 1), c2 = __shfl(cnt, 2), c3 = __shfl(cnt, 3);
  int off = (l >= 1 ? c0 : 0) + (l >= 2 ? c1 : 0) + (l >= 3 ? c2 : 0);
  if (l < 4) {
    int p = off;
    for (int r = 0; r < Rn; ++r) if (route[r] == l) grp[128 + p++] = r;
  }
  if (l == 0) {
    int cs[4] = {c0, c1, c2, c3};
    int os[4] = {0, c0, c0+c1, c0+c1+c2};
    int nt = 0;
    for (int e = 0; e < 4; ++e) {
      for (int s = 0; s < cs[e]; s += 8) {
        int nb = cs[e] - s; if (nb > 8) nb = 8;
        grp[8+nt*3+0] = e; grp[8+nt*3+1] = os[e]+s; grp[8+nt*3+2] = nb;
        ++nt;
      }
    }
    grp[0] = nt;
  }
}

__global__ __launch_bounds__(256) void convx_kernel(
    const float* __restrict__ x, f16* __restrict__ x16)
{
  const int i = (blockIdx.x*256 + threadIdx.x) * 8;
  float4 a = *(const float4*)(x + i);
  float4 b = *(const float4*)(x + i + 4);
  union { f16 h[8]; uint4 u; } p;
  p.h[0]=(f16)a.x; p.h[1]=(f16)a.y; p.h[2]=(f16)a.z; p.h[3]=(f16)a.w;
  p.h[4]=(f16)b.x; p.h[5]=(f16)b.y; p.h[6]=(f16)b.z; p.h[7]=(f16)b.w;
  *(uint4*)(x16 + i) = p.u;
}

// src [E][R][C] fp32 -> dst [E][C][R] fp16.  grid (C/64, R/64, E), block 256.
__global__ __launch_bounds__(256) void transcvt_kernel(
    const float* __restrict__ src, f16* __restrict__ dst, int R, int C)
{
  __shared__ f16 t[64][74];
  const int e  = blockIdx.z;
  const int r0 = blockIdx.y*64, c0 = blockIdx.x*64;
  const float* s = src + (size_t)e*R*C;
  f16* d = dst + (size_t)e*R*C;
  const int tid = threadIdx.x;
  const int i  = tid >> 2;
  const int j0 = (tid & 3) * 16;
  #pragma unroll
  for (int q = 0; q < 16; q += 4) {
    float4 v = *(const float4*)(s + (size_t)(r0+i)*C + c0 + j0 + q);
    t[i][j0+q+0]=(f16)v.x; t[i][j0+q+1]=(f16)v.y; t[i][j0+q+2]=(f16)v.z; t[i][j0+q+3]=(f16)v.w;
  }
  __syncthreads();
  f16 o[16];
  #pragma unroll
  for (int q = 0; q < 16; ++q) o[q] = t[j0+q][i];
  *(uint4*)(d + (size_t)(c0+i)*R + r0 + j0)     = *(uint4*)&o[0];
  *(uint4*)(d + (size_t)(c0+i)*R + r0 + j0 + 8) = *(uint4*)&o[8];
}

// Grouped GEMM, 1024 threads (16 waves, 4x4 wave grid), BM=256 fixed.
// wave-tile: 64 x (NI*16). g1: BN=256, NI=4; g2: BN=128, NI=2.
template<int KD, int ND, int BN, int NI, bool G1>
__global__ __launch_bounds__(1024, 4) void gemm_kernel(
    const f16* __restrict__ A16, const f16* __restrict__ B16,
    const float* __restrict__ bias, f16* __restrict__ oh,
    float* __restrict__ of, const int* __restrict__ grp,
    const float* __restrict__ wsf)
{
  const int ntiles = grp[0];
  const int tix = blockIdx.x;
  if (tix >= ntiles) return;
  const int e      = grp[8+tix*3+0];
  const int bstart = grp[8+tix*3+1];
  const int nb     = grp[8+tix*3+2];
  const int n0     = blockIdx.y * BN;
  const int tid    = threadIdx.x;

  extern __shared__ char smem[];
  f16 (*As)[72] = (f16(*)[72])smem;
  f16 (*Bs)[72] = (f16(*)[72])(smem + 256*72*2);
  int* rbeam = (int*)(smem + 256*72*2 + (size_t)BN*72*2);

  if (tid < 256) {
    int s = tid >> 5; if (s >= nb) s = nb - 1;
    rbeam[tid] = grp[128 + bstart + s];
  }

  // A staging: row tid>>2, 16 f16 at (tid&3)*16 (2x uint4)
  const int arow = tid >> 2;
  const int akb  = (tid & 3) * 16;
  int aslot = arow >> 5; if (aslot >= nb) aslot = nb - 1;
  const int ar = grp[128 + bstart + aslot];
  const size_t arowbase = G1 ? ((size_t)(ar>>1)*Tn + (arow&31)) * (size_t)KD
                             : ((size_t)ar*Tn + (arow&31)) * (size_t)KD;
  const f16* aptr = A16 + arowbase + akb;

  // B staging: threads-per-row = 1024/BN; elems/thread = BN/16; uint4s = BN/128
  constexpr int BNC = BN/128;                 // 2 (g1) or 1 (g2)
  constexpr int TPR = 1024/BN;                // 4 or 8
  const int brow = tid / TPR;
  const int bkb  = (tid % TPR) * (BN/16);
  const f16* bptr = B16 + (size_t)e*ND*KD + (size_t)(n0+brow)*KD + bkb;

  const int lane = tid & 63;
  const int w    = tid >> 6;
  const int wm   = w >> 2;
  const int wn   = w & 3;
  const int lr   = lane & 15;
  const int lk   = lane >> 4;
  const int rowA0 = wm*64;          // MI=4
  const int rowB0 = wn*(NI*16);

  constexpr int MI = 4;
  f32x4 acc[MI][NI];
  #pragma unroll
  for (int i=0;i<MI;++i)
    #pragma unroll
    for (int j=0;j<NI;++j) acc[i][j] = (f32x4){0.f,0.f,0.f,0.f};

  uint4 av[2], bv[BNC];
  #pragma unroll
  for (int q=0;q<2;++q) av[q] = *(const uint4*)(aptr + q*8);
  #pragma unroll
  for (int q=0;q<BNC;++q) bv[q] = *(const uint4*)(bptr + q*8);

  constexpr int NT = KD/64;
  for (int kt = 0; kt < NT; ++kt) {
    __syncthreads();
    #pragma unroll
    for (int q=0;q<2;++q) *(uint4*)&As[arow][akb + q*8] = av[q];
    #pragma unroll
    for (int q=0;q<BNC;++q) *(uint4*)&Bs[brow][bkb + q*8] = bv[q];
    __syncthreads();
    if (kt + 1 < NT) {
      const f16* ap = aptr + (size_t)(kt+1)*64;
      const f16* bp = bptr + (size_t)(kt+1)*64;
      #pragma unroll
      for (int q=0;q<2;++q) av[q] = *(const uint4*)(ap + q*8);
      #pragma unroll
      for (int q=0;q<BNC;++q) bv[q] = *(const uint4*)(bp + q*8);
    }
    #pragma unroll
    for (int ks = 0; ks < 2; ++ks) {
      f16x8 af[MI], bf[NI];
      #pragma unroll
      for (int mi=0;mi<MI;++mi)
        af[mi] = *(const f16x8*)&As[rowA0 + mi*16 + lr][ks*32 + lk*8];
      #pragma unroll
      for (int ni=0;ni<NI;++ni)
        bf[ni] = *(const f16x8*)&Bs[rowB0 + ni*16 + lr][ks*32 + lk*8];
      #pragma unroll
      for (int mi=0;mi<MI;++mi)
        #pragma unroll
        for (int ni=0;ni<NI;++ni)
          acc[mi][ni] = __builtin_amdgcn_mfma_f32_16x16x32_f16(af[mi], bf[ni], acc[mi][ni], 0, 0, 0);
    }
  }

  const int nvalid = nb * Tn;
  float bvals[NI];
  #pragma unroll
  for (int ni=0;ni<NI;++ni) bvals[ni] = bias[e*ND + n0 + rowB0 + ni*16 + lr];

  #pragma unroll
  for (int mi=0;mi<MI;++mi){
    #pragma unroll
    for (int j=0;j<4;++j){
      const int m = rowA0 + mi*16 + (lane>>4)*4 + j;
      if (m >= nvalid) continue;
      const int r = rbeam[m];
      const int t = m & 31;
      if (G1) {
        f16* orow = oh + ((size_t)r*Tn + t)*(size_t)ND + n0;
        #pragma unroll
        for (int ni=0;ni<NI;++ni){
          float v = acc[mi][ni][j] + bvals[ni];
          float g = 0.5f*v*(1.f + erff(v*0.70710678118f));
          orow[rowB0 + ni*16 + lr] = (f16)g;
        }
      } else {
        const float sc = wsf[512 + r];
        float* orow = of + ((size_t)r*Tn + t)*(size_t)Hn + n0;
        #pragma unroll
        for (int ni=0;ni<NI;++ni){
          float v = acc[mi][ni][j] + bvals[ni];
          orow[rowB0 + ni*16 + lr] = sc * v;
        }
      }
    }
  }
}

extern "C" void kernel_launch(void* const* d_in, const int* in_sizes, int n_in,
                              void* d_out, int out_size, void* d_ws, size_t ws_size,
                              hipStream_t stream)
{
  const float* x  = (const float*)d_in[0];
  const float* Wg = (const float*)d_in[1];
  const float* W1 = (const float*)d_in[2];
  const float* b1 = (const float*)d_in[3];
  const float* W2 = (const float*)d_in[4];
  const float* b2 = (const float*)d_in[5];
  float* out = (float*)d_out;
  char* ws = (char*)d_ws;
  float* wsf  = (float*)(ws + WS_WSF);
  int*   route= (int*)(ws + WS_ROUTE);
  int*   grp  = (int*)(ws + WS_GRP);
  f16*   x16  = (f16*)(ws + WS_X16);
  f16*   w1t  = (f16*)(ws + WS_W1T);
  f16*   w2t  = (f16*)(ws + WS_W2T);
  f16*   h1   = (f16*)(ws + WS_H1);

  gate_kernel<<<Bn, 64, 0, stream>>>(x, Wg, out, wsf, route);
  group_kernel<<<1, 64, 0, stream>>>(route, grp);
  loss_kernel<<<1, 64, 0, stream>>>(wsf, out);
  convx_kernel<<<1536, 256, 0, stream>>>(x, x16);
  transcvt_kernel<<<dim3(48,12,4), 256, 0, stream>>>(W1, w1t, Hn, Fn);
  transcvt_kernel<<<dim3(12,48,4), 256, 0, stream>>>(W2, w2t, Fn, Hn);

  auto g1 = gemm_kernel<Hn, Fn, 256, 4, true>;
  auto g2 = gemm_kernel<Fn, Hn, 128, 2, false>;
  const int sm1 = 256*72*2 + 256*72*2 + 1024;   // 74752 B
  const int sm2 = 256*72*2 + 128*72*2 + 1024;   // 56320 B
  hipFuncSetAttribute((const void*)g1, hipFuncAttributeMaxDynamicSharedMemorySize, sm1);
  hipFuncSetAttribute((const void*)g2, hipFuncAttributeMaxDynamicSharedMemorySize, sm2);
  g1<<<dim3(35,12), 1024, sm1, stream>>>(x16, w1t, b1, h1, nullptr, grp, wsf);
  g2<<<dim3(35,6),  1024, sm2, stream>>>(h1, w2t, b2, nullptr, out, grp, wsf);
}

// Round 4
// 207.393 us; speedup vs baseline: 7.2661x; 1.8185x over previous
//
#include <hip/hip_runtime.h>
#include <math.h>

typedef _Float16 f16;
typedef _Float16 f16x8 __attribute__((ext_vector_type(8)));
typedef float f32x4 __attribute__((ext_vector_type(4)));

#define Bn 128
#define Tn 32
#define Hn 768
#define En 4
#define Fn 3072
#define Rn 256

static constexpr size_t OUT_ELEMS  = (size_t)Rn*Tn*Hn;
static constexpr size_t SCORES_OFF = OUT_ELEMS;
static constexpr size_t ROUTE_OFF  = OUT_ELEMS + Rn;
static constexpr size_t BIDX_OFF   = OUT_ELEMS + 2*Rn;
static constexpr size_t LOSS_OFF   = OUT_ELEMS + 3*Rn;

// ws byte offsets
#define WS_WSF    0u
#define WS_ROUTE  4096u
#define WS_GRP    8192u
#define WS_X16    16384u
#define WS_W1T    (WS_X16 + 2u*Bn*Tn*Hn)
#define WS_W2T    (WS_W1T + 2u*En*Hn*Fn)
#define WS_H1     (WS_W2T + 2u*En*Fn*Hn)

#define GLOAD16(g, l) __builtin_amdgcn_global_load_lds( \
    (const __attribute__((address_space(1))) unsigned int*)(g), \
    (__attribute__((address_space(3))) unsigned int*)(l), 16, 0, 0)

__device__ __forceinline__ float fast_gelu(float v) {
  // exact gelu via A&S 7.1.26 erf approx (|eps| <= 1.5e-7)
  float s = v * 0.70710678118f;
  float a = fabsf(s);
  float t = 1.0f / (1.0f + 0.3275911f * a);
  float y = t*(0.254829592f + t*(-0.284496736f + t*(1.421413741f +
            t*(-1.453152027f + t*1.061405429f))));
  float er = 1.0f - y * __expf(-a*a);
  er = (s < 0.0f) ? -er : er;
  return 0.5f * v * (1.0f + er);
}

__global__ __launch_bounds__(64) void gate_kernel(
    const float* __restrict__ x, const float* __restrict__ Wg,
    float* __restrict__ out, float* __restrict__ wsf, int* __restrict__ route)
{
  const int b = blockIdx.x;
  const int l = threadIdx.x;
  float acc0=0.f, acc1=0.f, acc2=0.f, acc3=0.f;
  const float* xb = x + (size_t)b*Tn*Hn;
  for (int h = l; h < Hn; h += 64) {
    float xa = 0.f;
    #pragma unroll
    for (int t = 0; t < Tn; ++t) xa += xb[t*Hn + h];
    xa *= (1.0f/Tn);
    acc0 += xa * Wg[0*Hn + h];
    acc1 += xa * Wg[1*Hn + h];
    acc2 += xa * Wg[2*Hn + h];
    acc3 += xa * Wg[3*Hn + h];
  }
  #pragma unroll
  for (int o = 32; o > 0; o >>= 1) {
    acc0 += __shfl_down(acc0, o);
    acc1 += __shfl_down(acc1, o);
    acc2 += __shfl_down(acc2, o);
    acc3 += __shfl_down(acc3, o);
  }
  if (l == 0) {
    float lg[4] = {acc0, acc1, acc2, acc3};
    float m = fmaxf(fmaxf(lg[0],lg[1]), fmaxf(lg[2],lg[3]));
    float p[4]; float s = 0.f;
    #pragma unroll
    for (int e = 0; e < 4; ++e) { p[e] = expf(lg[e]-m); s += p[e]; }
    float inv = 1.f/s;
    #pragma unroll
    for (int e = 0; e < 4; ++e) { p[e] *= inv; wsf[b*4+e] = p[e]; }
    int i1 = 0;
    #pragma unroll
    for (int e = 1; e < 4; ++e) if (p[e] > p[i1]) i1 = e;
    int i2 = (i1 == 0) ? 1 : 0;
    #pragma unroll
    for (int e = 0; e < 4; ++e) if (e != i1 && p[e] > p[i2]) i2 = e;
    int idx[2] = {i1, i2};
    #pragma unroll
    for (int k = 0; k < 2; ++k) {
      int r = 2*b + k;
      float pv = p[idx[k]];
      wsf[512 + r] = pv;
      route[r] = idx[k];
      out[SCORES_OFF + r] = pv;
      out[ROUTE_OFF  + r] = (float)idx[k];
      out[BIDX_OFF   + r] = (float)r;
    }
  }
}

__global__ __launch_bounds__(64) void loss_kernel(
    const float* __restrict__ wsf, float* __restrict__ out)
{
  const int l = threadIdx.x;
  float i0=0.f,i1=0.f,i2=0.f,i3=0.f;
  for (int b = l; b < Bn; b += 64) {
    i0 += wsf[b*4+0]; i1 += wsf[b*4+1]; i2 += wsf[b*4+2]; i3 += wsf[b*4+3];
  }
  #pragma unroll
  for (int o = 32; o > 0; o >>= 1) {
    i0 += __shfl_down(i0,o); i1 += __shfl_down(i1,o);
    i2 += __shfl_down(i2,o); i3 += __shfl_down(i3,o);
  }
  if (l == 0) {
    float mean = 0.25f*(i0+i1+i2+i3);
    float d0=i0-mean, d1=i1-mean, d2=i2-mean, d3=i3-mean;
    float var = (d0*d0+d1*d1+d2*d2+d3*d3) * (1.f/3.f);
    out[LOSS_OFF] = var / (mean*mean);
  }
}

// grp layout (ints): [0]=ntiles; tiles at [8+3i] = {e, bstart, nbeams}; blist at [128..383]
__global__ __launch_bounds__(64) void group_kernel(
    const int* __restrict__ route, int* __restrict__ grp)
{
  const int l = threadIdx.x;
  int cnt = 0;
  if (l < 4) { for (int r = 0; r < Rn; ++r) cnt += (route[r] == l); }
  int c0 = __shfl(cnt, 0), c1 = __shfl(cnt, 1), c2 = __shfl(cnt, 2), c3 = __shfl(cnt, 3);
  int off = (l >= 1 ? c0 : 0) + (l >= 2 ? c1 : 0) + (l >= 3 ? c2 : 0);
  if (l < 4) {
    int p = off;
    for (int r = 0; r < Rn; ++r) if (route[r] == l) grp[128 + p++] = r;
  }
  if (l == 0) {
    int cs[4] = {c0, c1, c2, c3};
    int os[4] = {0, c0, c0+c1, c0+c1+c2};
    int nt = 0;
    for (int e = 0; e < 4; ++e) {
      for (int s = 0; s < cs[e]; s += 8) {
        int nb = cs[e] - s; if (nb > 8) nb = 8;
        grp[8+nt*3+0] = e; grp[8+nt*3+1] = os[e]+s; grp[8+nt*3+2] = nb;
        ++nt;
      }
    }
    grp[0] = nt;
  }
}

__global__ __launch_bounds__(256) void convx_kernel(
    const float* __restrict__ x, f16* __restrict__ x16)
{
  const int i = (blockIdx.x*256 + threadIdx.x) * 8;
  float4 a = *(const float4*)(x + i);
  float4 b = *(const float4*)(x + i + 4);
  union { f16 h[8]; uint4 u; } p;
  p.h[0]=(f16)a.x; p.h[1]=(f16)a.y; p.h[2]=(f16)a.z; p.h[3]=(f16)a.w;
  p.h[4]=(f16)b.x; p.h[5]=(f16)b.y; p.h[6]=(f16)b.z; p.h[7]=(f16)b.w;
  *(uint4*)(x16 + i) = p.u;
}

// src [E][R][C] fp32 -> dst [E][C][R] fp16.  grid (C/64, R/64, E), block 256.
__global__ __launch_bounds__(256) void transcvt_kernel(
    const float* __restrict__ src, f16* __restrict__ dst, int R, int C)
{
  __shared__ f16 t[64][74];
  const int e  = blockIdx.z;
  const int r0 = blockIdx.y*64, c0 = blockIdx.x*64;
  const float* s = src + (size_t)e*R*C;
  f16* d = dst + (size_t)e*R*C;
  const int tid = threadIdx.x;
  const int i  = tid >> 2;
  const int j0 = (tid & 3) * 16;
  #pragma unroll
  for (int q = 0; q < 16; q += 4) {
    float4 v = *(const float4*)(s + (size_t)(r0+i)*C + c0 + j0 + q);
    t[i][j0+q+0]=(f16)v.x; t[i][j0+q+1]=(f16)v.y; t[i][j0+q+2]=(f16)v.z; t[i][j0+q+3]=(f16)v.w;
  }
  __syncthreads();
  f16 o[16];
  #pragma unroll
  for (int q = 0; q < 16; ++q) o[q] = t[j0+q][i];
  *(uint4*)(d + (size_t)(c0+i)*R + r0 + j0)     = *(uint4*)&o[0];
  *(uint4*)(d + (size_t)(c0+i)*R + r0 + j0 + 8) = *(uint4*)&o[8];
}

// Grouped GEMM, 1024 thr (16 waves 4x4), BM=256, BK=64, global_load_lds dbuf,
// XOR-swizzled LDS (linear dest + pre-swizzled global src), LDS-staged epilogue.
// LDS: A[2][256][64]f16 @0/32768; B[2][BN][64]f16 @65536; epilogue Cst[256][512B] @0.
template<int KD, int ND, int BN, int NI, bool G1>
__global__ __launch_bounds__(1024, 4) void gemm_kernel(
    const f16* __restrict__ A16, const f16* __restrict__ B16,
    const float* __restrict__ bias, f16* __restrict__ oh,
    float* __restrict__ of, const int* __restrict__ grp,
    const float* __restrict__ wsf)
{
  const int ntiles = grp[0];
  const int tix = blockIdx.x;
  if (tix >= ntiles) return;
  const int e      = grp[8+tix*3+0];
  const int bstart = grp[8+tix*3+1];
  const int nb     = grp[8+tix*3+2];
  const int n0     = blockIdx.y * BN;
  const int tid    = threadIdx.x;
  const int lane   = tid & 63;
  const int w      = tid >> 6;

  extern __shared__ __align__(16) char smem[];
  constexpr int BNB = BN * 128;          // B buffer bytes
  constexpr int BI  = BN / 128;          // B gload instrs per wave (2 or 1)

  // ---- staging source addresses (pre-swizzled: LDS slot (row,c) holds global unit c^(row&7)) ----
  const int srow8 = lane >> 3;           // row within 8-row chunk
  const int sunit = (lane & 7) ^ srow8;  // swizzled source 16B-unit
  const f16* asrc[2];
  #pragma unroll
  for (int i = 0; i < 2; ++i) {
    int row = (w*2 + i)*8 + srow8;
    int slot = row >> 5; if (slot >= nb) slot = nb - 1;
    int beam = grp[128 + bstart + slot];
    size_t rbase = G1 ? ((size_t)(beam>>1)*Tn + (row&31)) * (size_t)KD
                      : ((size_t)beam*Tn + (row&31)) * (size_t)KD;
    asrc[i] = A16 + rbase + sunit*8;
  }
  const f16* bsrc[BI];
  #pragma unroll
  for (int i = 0; i < BI; ++i) {
    int row = (w*BI + i)*8 + srow8;
    bsrc[i] = B16 + (size_t)e*ND*KD + (size_t)(n0 + row)*KD + sunit*8;
  }

  // ---- fragment geometry ----
  const int wm = w >> 2, wn = w & 3;
  const int lr = lane & 15, lk = lane >> 4;
  const int rowA0 = wm*64;
  const int rowB0 = wn*(NI*16);
  const int r7 = lr & 7;
  const int u0 = (lk ^ r7) * 16;         // byte offset of 16B unit, ks=0

  constexpr int MI = 4;
  f32x4 acc[MI][NI];
  #pragma unroll
  for (int i=0;i<MI;++i)
    #pragma unroll
    for (int j=0;j<NI;++j) acc[i][j] = (f32x4){0.f,0.f,0.f,0.f};

  constexpr int NT = KD/64;
  // prologue stage
  {
    char* Ad = smem + (w*2)*1024;
    GLOAD16(asrc[0], Ad);
    GLOAD16(asrc[1], Ad + 1024);
    char* Bd = smem + 65536 + (w*BI)*1024;
    #pragma unroll
    for (int i = 0; i < BI; ++i) GLOAD16(bsrc[i], Bd + i*1024);
  }
  __syncthreads();

  int buf = 0;
  for (int kt = 0; kt < NT; ++kt) {
    if (kt + 1 < NT) {
      const int nxt = buf ^ 1;
      char* Ad = smem + nxt*32768 + (w*2)*1024;
      GLOAD16(asrc[0] + (kt+1)*64, Ad);
      GLOAD16(asrc[1] + (kt+1)*64, Ad + 1024);
      char* Bd = smem + 65536 + nxt*BNB + (w*BI)*1024;
      #pragma unroll
      for (int i = 0; i < BI; ++i) GLOAD16(bsrc[i] + (kt+1)*64, Bd + i*1024);
    }
    const char* Ab = smem + buf*32768;
    const char* Bb = smem + 65536 + buf*BNB;
    #pragma unroll
    for (int ks = 0; ks < 2; ++ks) {
      const int ub = u0 ^ (ks << 6);     // unit ^= 4 -> byte ^= 64
      f16x8 af[MI], bf[NI];
      #pragma unroll
      for (int mi=0;mi<MI;++mi)
        af[mi] = *(const f16x8*)(Ab + (rowA0 + mi*16 + lr)*128 + ub);
      #pragma unroll
      for (int ni=0;ni<NI;++ni)
        bf[ni] = *(const f16x8*)(Bb + (rowB0 + ni*16 + lr)*128 + ub);
      #pragma unroll
      for (int mi=0;mi<MI;++mi)
        #pragma unroll
        for (int ni=0;ni<NI;++ni)
          acc[mi][ni] = __builtin_amdgcn_mfma_f32_16x16x32_f16(af[mi], bf[ni], acc[mi][ni], 0, 0, 0);
    }
    __syncthreads();
    buf ^= 1;
  }

  // ---- epilogue: acc -> swizzled LDS tile (rows of 512 B) -> coalesced stores ----
  const int nvalid = nb * Tn;
  char* cst = smem;

  if (G1) {
    float bvals[NI];
    #pragma unroll
    for (int ni=0;ni<NI;++ni) bvals[ni] = bias[e*ND + n0 + rowB0 + ni*16 + lr];
    #pragma unroll
    for (int mi=0;mi<MI;++mi){
      #pragma unroll
      for (int j=0;j<4;++j){
        const int m = rowA0 + mi*16 + (lane>>4)*4 + j;
        const int m7 = m & 7;
        #pragma unroll
        for (int ni=0;ni<NI;++ni){
          const int n = rowB0 + ni*16 + lr;
          float v = acc[mi][ni][j] + bvals[ni];
          f16 hv = (f16)fast_gelu(v);
          *(f16*)(cst + m*512 + (((n>>3)^m7)<<4) + (n&7)*2) = hv;
        }
      }
    }
  } else {
    #pragma unroll
    for (int mi=0;mi<MI;++mi){
      #pragma unroll
      for (int j=0;j<4;++j){
        const int m = rowA0 + mi*16 + (lane>>4)*4 + j;
        const int m7 = m & 7;
        #pragma unroll
        for (int ni=0;ni<NI;++ni){
          const int n = rowB0 + ni*16 + lr;
          *(float*)(cst + m*512 + (((n>>2)^m7)<<4) + (n&3)*4) = acc[mi][ni][j];
        }
      }
    }
  }
  __syncthreads();

  const int u  = tid & 31;
  const int tr = tid >> 5;
  if (G1) {
    #pragma unroll
    for (int it = 0; it < 8; ++it) {
      const int r = it*32 + tr;
      if (r >= nvalid) continue;
      const int beam = grp[128 + bstart + (r>>5)];
      uint4 v = *(const uint4*)(cst + r*512 + (((u&24)|((u&7)^(r&7)))<<4));
      *(uint4*)(oh + ((size_t)beam*Tn + (r&31))*(size_t)ND + n0 + u*8) = v;
    }
  } else {
    float4 b4 = *(const float4*)(bias + e*ND + n0 + u*4);
    #pragma unroll
    for (int it = 0; it < 8; ++it) {
      const int r = it*32 + tr;
      if (r >= nvalid) continue;
      const int beam = grp[128 + bstart + (r>>5)];
      const float sc = wsf[512 + beam];
      float4 v = *(const float4*)(cst + r*512 + (((u&24)|((u&7)^(r&7)))<<4));
      v.x = (v.x + b4.x)*sc; v.y = (v.y + b4.y)*sc;
      v.z = (v.z + b4.z)*sc; v.w = (v.w + b4.w)*sc;
      *(float4*)(of + ((size_t)beam*Tn + (r&31))*(size_t)Hn + n0 + u*4) = v;
    }
  }
}

extern "C" void kernel_launch(void* const* d_in, const int* in_sizes, int n_in,
                              void* d_out, int out_size, void* d_ws, size_t ws_size,
                              hipStream_t stream)
{
  const float* x  = (const float*)d_in[0];
  const float* Wg = (const float*)d_in[1];
  const float* W1 = (const float*)d_in[2];
  const float* b1 = (const float*)d_in[3];
  const float* W2 = (const float*)d_in[4];
  const float* b2 = (const float*)d_in[5];
  float* out = (float*)d_out;
  char* ws = (char*)d_ws;
  float* wsf  = (float*)(ws + WS_WSF);
  int*   route= (int*)(ws + WS_ROUTE);
  int*   grp  = (int*)(ws + WS_GRP);
  f16*   x16  = (f16*)(ws + WS_X16);
  f16*   w1t  = (f16*)(ws + WS_W1T);
  f16*   w2t  = (f16*)(ws + WS_W2T);
  f16*   h1   = (f16*)(ws + WS_H1);

  gate_kernel<<<Bn, 64, 0, stream>>>(x, Wg, out, wsf, route);
  group_kernel<<<1, 64, 0, stream>>>(route, grp);
  loss_kernel<<<1, 64, 0, stream>>>(wsf, out);
  convx_kernel<<<1536, 256, 0, stream>>>(x, x16);
  transcvt_kernel<<<dim3(48,12,4), 256, 0, stream>>>(W1, w1t, Hn, Fn);
  transcvt_kernel<<<dim3(12,48,4), 256, 0, stream>>>(W2, w2t, Fn, Hn);

  auto g1 = gemm_kernel<Hn, Fn, 256, 4, true>;
  auto g2 = gemm_kernel<Fn, Hn, 128, 2, false>;
  const int smB = 131072;
  hipFuncSetAttribute((const void*)g1, hipFuncAttributeMaxDynamicSharedMemorySize, smB);
  hipFuncSetAttribute((const void*)g2, hipFuncAttributeMaxDynamicSharedMemorySize, smB);
  g1<<<dim3(35,12), 1024, smB, stream>>>(x16, w1t, b1, h1, nullptr, grp, wsf);
  g2<<<dim3(35,6),  1024, smB, stream>>>(h1, w2t, b2, nullptr, out, grp, wsf);
}

// Round 5
// 200.038 us; speedup vs baseline: 7.5333x; 1.0368x over previous
//
#include <hip/hip_runtime.h>
#include <math.h>

typedef _Float16 f16;
typedef _Float16 f16x8 __attribute__((ext_vector_type(8)));
typedef float f32x4 __attribute__((ext_vector_type(4)));

#define Bn 128
#define Tn 32
#define Hn 768
#define En 4
#define Fn 3072
#define Rn 256

static constexpr size_t OUT_ELEMS  = (size_t)Rn*Tn*Hn;
static constexpr size_t SCORES_OFF = OUT_ELEMS;
static constexpr size_t ROUTE_OFF  = OUT_ELEMS + Rn;
static constexpr size_t BIDX_OFF   = OUT_ELEMS + 2*Rn;
static constexpr size_t LOSS_OFF   = OUT_ELEMS + 3*Rn;

// ws byte offsets
#define WS_WSF    0u
#define WS_ROUTE  4096u
#define WS_GRP    8192u
#define WS_X16    16384u
#define WS_W1T    (WS_X16 + 2u*Bn*Tn*Hn)
#define WS_W2T    (WS_W1T + 2u*En*Hn*Fn)
#define WS_H1     (WS_W2T + 2u*En*Fn*Hn)

#define GLOAD16(g, l) __builtin_amdgcn_global_load_lds( \
    (const __attribute__((address_space(1))) unsigned int*)(g), \
    (__attribute__((address_space(3))) unsigned int*)(l), 16, 0, 0)

__device__ __forceinline__ float fast_gelu(float v) {
  // exact gelu via A&S 7.1.26 erf approx (|eps| <= 1.5e-7)
  float s = v * 0.70710678118f;
  float a = fabsf(s);
  float t = 1.0f / (1.0f + 0.3275911f * a);
  float y = t*(0.254829592f + t*(-0.284496736f + t*(1.421413741f +
            t*(-1.453152027f + t*1.061405429f))));
  float er = 1.0f - y * __expf(-a*a);
  er = (s < 0.0f) ? -er : er;
  return 0.5f * v * (1.0f + er);
}

__global__ __launch_bounds__(64) void gate_kernel(
    const float* __restrict__ x, const float* __restrict__ Wg,
    float* __restrict__ out, float* __restrict__ wsf, int* __restrict__ route)
{
  const int b = blockIdx.x;
  const int l = threadIdx.x;
  float acc0=0.f, acc1=0.f, acc2=0.f, acc3=0.f;
  const float* xb = x + (size_t)b*Tn*Hn;
  for (int h = l; h < Hn; h += 64) {
    float xa = 0.f;
    #pragma unroll
    for (int t = 0; t < Tn; ++t) xa += xb[t*Hn + h];
    xa *= (1.0f/Tn);
    acc0 += xa * Wg[0*Hn + h];
    acc1 += xa * Wg[1*Hn + h];
    acc2 += xa * Wg[2*Hn + h];
    acc3 += xa * Wg[3*Hn + h];
  }
  #pragma unroll
  for (int o = 32; o > 0; o >>= 1) {
    acc0 += __shfl_down(acc0, o);
    acc1 += __shfl_down(acc1, o);
    acc2 += __shfl_down(acc2, o);
    acc3 += __shfl_down(acc3, o);
  }
  if (l == 0) {
    float lg[4] = {acc0, acc1, acc2, acc3};
    float m = fmaxf(fmaxf(lg[0],lg[1]), fmaxf(lg[2],lg[3]));
    float p[4]; float s = 0.f;
    #pragma unroll
    for (int e = 0; e < 4; ++e) { p[e] = expf(lg[e]-m); s += p[e]; }
    float inv = 1.f/s;
    #pragma unroll
    for (int e = 0; e < 4; ++e) { p[e] *= inv; wsf[b*4+e] = p[e]; }
    int i1 = 0;
    #pragma unroll
    for (int e = 1; e < 4; ++e) if (p[e] > p[i1]) i1 = e;
    int i2 = (i1 == 0) ? 1 : 0;
    #pragma unroll
    for (int e = 0; e < 4; ++e) if (e != i1 && p[e] > p[i2]) i2 = e;
    int idx[2] = {i1, i2};
    #pragma unroll
    for (int k = 0; k < 2; ++k) {
      int r = 2*b + k;
      float pv = p[idx[k]];
      wsf[512 + r] = pv;
      route[r] = idx[k];
      out[SCORES_OFF + r] = pv;
      out[ROUTE_OFF  + r] = (float)idx[k];
      out[BIDX_OFF   + r] = (float)r;
    }
  }
}

__global__ __launch_bounds__(64) void loss_kernel(
    const float* __restrict__ wsf, float* __restrict__ out)
{
  const int l = threadIdx.x;
  float i0=0.f,i1=0.f,i2=0.f,i3=0.f;
  for (int b = l; b < Bn; b += 64) {
    i0 += wsf[b*4+0]; i1 += wsf[b*4+1]; i2 += wsf[b*4+2]; i3 += wsf[b*4+3];
  }
  #pragma unroll
  for (int o = 32; o > 0; o >>= 1) {
    i0 += __shfl_down(i0,o); i1 += __shfl_down(i1,o);
    i2 += __shfl_down(i2,o); i3 += __shfl_down(i3,o);
  }
  if (l == 0) {
    float mean = 0.25f*(i0+i1+i2+i3);
    float d0=i0-mean, d1=i1-mean, d2=i2-mean, d3=i3-mean;
    float var = (d0*d0+d1*d1+d2*d2+d3*d3) * (1.f/3.f);
    out[LOSS_OFF] = var / (mean*mean);
  }
}

// grp layout (ints): [0]=ntiles; tiles at [8+3i] = {e, bstart, nbeams}; blist at [128..383]
__global__ __launch_bounds__(64) void group_kernel(
    const int* __restrict__ route, int* __restrict__ grp)
{
  const int l = threadIdx.x;
  int cnt = 0;
  if (l < 4) { for (int r = 0; r < Rn; ++r) cnt += (route[r] == l); }
  int c0 = __shfl(cnt, 0), c1 = __shfl(cnt, 1), c2 = __shfl(cnt, 2), c3 = __shfl(cnt, 3);
  int off = (l >= 1 ? c0 : 0) + (l >= 2 ? c1 : 0) + (l >= 3 ? c2 : 0);
  if (l < 4) {
    int p = off;
    for (int r = 0; r < Rn; ++r) if (route[r] == l) grp[128 + p++] = r;
  }
  if (l == 0) {
    int cs[4] = {c0, c1, c2, c3};
    int os[4] = {0, c0, c0+c1, c0+c1+c2};
    int nt = 0;
    for (int e = 0; e < 4; ++e) {
      for (int s = 0; s < cs[e]; s += 8) {
        int nb = cs[e] - s; if (nb > 8) nb = 8;
        grp[8+nt*3+0] = e; grp[8+nt*3+1] = os[e]+s; grp[8+nt*3+2] = nb;
        ++nt;
      }
    }
    grp[0] = nt;
  }
}

__global__ __launch_bounds__(256) void convx_kernel(
    const float* __restrict__ x, f16* __restrict__ x16)
{
  const int i = (blockIdx.x*256 + threadIdx.x) * 8;
  float4 a = *(const float4*)(x + i);
  float4 b = *(const float4*)(x + i + 4);
  union { f16 h[8]; uint4 u; } p;
  p.h[0]=(f16)a.x; p.h[1]=(f16)a.y; p.h[2]=(f16)a.z; p.h[3]=(f16)a.w;
  p.h[4]=(f16)b.x; p.h[5]=(f16)b.y; p.h[6]=(f16)b.z; p.h[7]=(f16)b.w;
  *(uint4*)(x16 + i) = p.u;
}

// src [E][R][C] fp32 -> dst [E][C][R] fp16.  grid (C/64, R/64, E), block 256.
__global__ __launch_bounds__(256) void transcvt_kernel(
    const float* __restrict__ src, f16* __restrict__ dst, int R, int C)
{
  __shared__ f16 t[64][74];
  const int e  = blockIdx.z;
  const int r0 = blockIdx.y*64, c0 = blockIdx.x*64;
  const float* s = src + (size_t)e*R*C;
  f16* d = dst + (size_t)e*R*C;
  const int tid = threadIdx.x;
  const int i  = tid >> 2;
  const int j0 = (tid & 3) * 16;
  #pragma unroll
  for (int q = 0; q < 16; q += 4) {
    float4 v = *(const float4*)(s + (size_t)(r0+i)*C + c0 + j0 + q);
    t[i][j0+q+0]=(f16)v.x; t[i][j0+q+1]=(f16)v.y; t[i][j0+q+2]=(f16)v.z; t[i][j0+q+3]=(f16)v.w;
  }
  __syncthreads();
  f16 o[16];
  #pragma unroll
  for (int q = 0; q < 16; ++q) o[q] = t[j0+q][i];
  *(uint4*)(d + (size_t)(c0+i)*R + r0 + j0)     = *(uint4*)&o[0];
  *(uint4*)(d + (size_t)(c0+i)*R + r0 + j0 + 8) = *(uint4*)&o[8];
}

// Grouped GEMM, 1024 thr (16 waves 4x4), BM=256, BK=64, global_load_lds dbuf,
// counted-vmcnt raw-barrier pipeline (T4) + setprio (T5), XOR-swizzled LDS,
// LDS-staged epilogue.  1D grid, y-major: bid -> (tix=bid/NY, ny=bid%NY).
template<int KD, int ND, int BN, int NI, bool G1>
__global__ __launch_bounds__(1024, 4) void gemm_kernel(
    const f16* __restrict__ A16, const f16* __restrict__ B16,
    const float* __restrict__ bias, f16* __restrict__ oh,
    float* __restrict__ of, const int* __restrict__ grp,
    const float* __restrict__ wsf)
{
  constexpr int NY = ND / BN;
  const int ntiles = grp[0];
  const int tix = blockIdx.x / NY;
  const int ny  = blockIdx.x % NY;
  if (tix >= ntiles) return;
  const int e      = grp[8+tix*3+0];
  const int bstart = grp[8+tix*3+1];
  const int nb     = grp[8+tix*3+2];
  const int n0     = ny * BN;
  const int tid    = threadIdx.x;
  const int lane   = tid & 63;
  const int w      = tid >> 6;

  extern __shared__ __align__(16) char smem[];
  constexpr int BNB = BN * 128;          // B buffer bytes
  constexpr int BI  = BN / 128;          // B gload instrs per wave (2 or 1)
  constexpr int NLD = 2 + BI;            // gloads per wave per k-tile

  // ---- staging source addresses (pre-swizzled: LDS slot (row,c) holds global unit c^(row&7)) ----
  const int srow8 = lane >> 3;           // row within 8-row chunk
  const int sunit = (lane & 7) ^ srow8;  // swizzled source 16B-unit
  const f16* asrc[2];
  #pragma unroll
  for (int i = 0; i < 2; ++i) {
    int row = (w*2 + i)*8 + srow8;
    int slot = row >> 5; if (slot >= nb) slot = nb - 1;
    int beam = grp[128 + bstart + slot];
    size_t rbase = G1 ? ((size_t)(beam>>1)*Tn + (row&31)) * (size_t)KD
                      : ((size_t)beam*Tn + (row&31)) * (size_t)KD;
    asrc[i] = A16 + rbase + sunit*8;
  }
  const f16* bsrc[BI];
  #pragma unroll
  for (int i = 0; i < BI; ++i) {
    int row = (w*BI + i)*8 + srow8;
    bsrc[i] = B16 + (size_t)e*ND*KD + (size_t)(n0 + row)*KD + sunit*8;
  }

  // ---- fragment geometry ----
  const int wm = w >> 2, wn = w & 3;
  const int lr = lane & 15, lk = lane >> 4;
  const int rowA0 = wm*64;
  const int rowB0 = wn*(NI*16);
  const int r7 = lr & 7;
  const int u0 = (lk ^ r7) * 16;         // byte offset of 16B unit, ks=0

  constexpr int MI = 4;
  f32x4 acc[MI][NI];
  #pragma unroll
  for (int i=0;i<MI;++i)
    #pragma unroll
    for (int j=0;j<NI;++j) acc[i][j] = (f32x4){0.f,0.f,0.f,0.f};

  constexpr int NT = KD/64;

  auto STAGE = [&](int bsel, int kt2) {
    char* Ad = smem + bsel*32768 + (w*2)*1024;
    GLOAD16(asrc[0] + kt2*64, Ad);
    GLOAD16(asrc[1] + kt2*64, Ad + 1024);
    char* Bd = smem + 65536 + bsel*BNB + (w*BI)*1024;
    #pragma unroll
    for (int i = 0; i < BI; ++i) GLOAD16(bsrc[i] + kt2*64, Bd + i*1024);
  };

  // prologue stage (k-tile 0 -> buf 0)
  STAGE(0, 0);

  int buf = 0;
  for (int kt = 0; kt < NT; ++kt) {
    if (kt + 1 < NT) {
      STAGE(buf ^ 1, kt + 1);
      // wait only for the OLDEST NLD loads (this tile); next tile stays in flight
      asm volatile("s_waitcnt vmcnt(%0)" :: "i"(NLD) : "memory");
    } else {
      asm volatile("s_waitcnt vmcnt(0)" ::: "memory");
    }
    __builtin_amdgcn_sched_barrier(0);
    __builtin_amdgcn_s_barrier();
    __builtin_amdgcn_sched_barrier(0);

    const char* Ab = smem + buf*32768;
    const char* Bb = smem + 65536 + buf*BNB;
    #pragma unroll
    for (int ks = 0; ks < 2; ++ks) {
      const int ub = u0 ^ (ks << 6);     // unit ^= 4 -> byte ^= 64
      f16x8 af[MI], bf[NI];
      #pragma unroll
      for (int mi=0;mi<MI;++mi)
        af[mi] = *(const f16x8*)(Ab + (rowA0 + mi*16 + lr)*128 + ub);
      #pragma unroll
      for (int ni=0;ni<NI;++ni)
        bf[ni] = *(const f16x8*)(Bb + (rowB0 + ni*16 + lr)*128 + ub);
      __builtin_amdgcn_s_setprio(1);
      #pragma unroll
      for (int mi=0;mi<MI;++mi)
        #pragma unroll
        for (int ni=0;ni<NI;++ni)
          acc[mi][ni] = __builtin_amdgcn_mfma_f32_16x16x32_f16(af[mi], bf[ni], acc[mi][ni], 0, 0, 0);
      __builtin_amdgcn_s_setprio(0);
    }
    __builtin_amdgcn_s_barrier();        // all waves done reading buf before it is restaged
    __builtin_amdgcn_sched_barrier(0);
    buf ^= 1;
  }

  // ---- epilogue: acc -> swizzled LDS tile (rows of 512 B) -> coalesced stores ----
  const int nvalid = nb * Tn;
  char* cst = smem;

  if (G1) {
    float bvals[NI];
    #pragma unroll
    for (int ni=0;ni<NI;++ni) bvals[ni] = bias[e*ND + n0 + rowB0 + ni*16 + lr];
    #pragma unroll
    for (int mi=0;mi<MI;++mi){
      #pragma unroll
      for (int j=0;j<4;++j){
        const int m = rowA0 + mi*16 + (lane>>4)*4 + j;
        const int m7 = m & 7;
        #pragma unroll
        for (int ni=0;ni<NI;++ni){
          const int n = rowB0 + ni*16 + lr;
          float v = acc[mi][ni][j] + bvals[ni];
          f16 hv = (f16)fast_gelu(v);
          *(f16*)(cst + m*512 + (((n>>3)^m7)<<4) + (n&7)*2) = hv;
        }
      }
    }
  } else {
    #pragma unroll
    for (int mi=0;mi<MI;++mi){
      #pragma unroll
      for (int j=0;j<4;++j){
        const int m = rowA0 + mi*16 + (lane>>4)*4 + j;
        const int m7 = m & 7;
        #pragma unroll
        for (int ni=0;ni<NI;++ni){
          const int n = rowB0 + ni*16 + lr;
          *(float*)(cst + m*512 + (((n>>2)^m7)<<4) + (n&3)*4) = acc[mi][ni][j];
        }
      }
    }
  }
  __syncthreads();

  const int u  = tid & 31;
  const int tr = tid >> 5;
  if (G1) {
    #pragma unroll
    for (int it = 0; it < 8; ++it) {
      const int r = it*32 + tr;
      if (r >= nvalid) continue;
      const int beam = grp[128 + bstart + (r>>5)];
      uint4 v = *(const uint4*)(cst + r*512 + (((u&24)|((u&7)^(r&7)))<<4));
      *(uint4*)(oh + ((size_t)beam*Tn + (r&31))*(size_t)ND + n0 + u*8) = v;
    }
  } else {
    float4 b4 = *(const float4*)(bias + e*ND + n0 + u*4);
    #pragma unroll
    for (int it = 0; it < 8; ++it) {
      const int r = it*32 + tr;
      if (r >= nvalid) continue;
      const int beam = grp[128 + bstart + (r>>5)];
      const float sc = wsf[512 + beam];
      float4 v = *(const float4*)(cst + r*512 + (((u&24)|((u&7)^(r&7)))<<4));
      v.x = (v.x + b4.x)*sc; v.y = (v.y + b4.y)*sc;
      v.z = (v.z + b4.z)*sc; v.w = (v.w + b4.w)*sc;
      *(float4*)(of + ((size_t)beam*Tn + (r&31))*(size_t)Hn + n0 + u*4) = v;
    }
  }
}

extern "C" void kernel_launch(void* const* d_in, const int* in_sizes, int n_in,
                              void* d_out, int out_size, void* d_ws, size_t ws_size,
                              hipStream_t stream)
{
  const float* x  = (const float*)d_in[0];
  const float* Wg = (const float*)d_in[1];
  const float* W1 = (const float*)d_in[2];
  const float* b1 = (const float*)d_in[3];
  const float* W2 = (const float*)d_in[4];
  const float* b2 = (const float*)d_in[5];
  float* out = (float*)d_out;
  char* ws = (char*)d_ws;
  float* wsf  = (float*)(ws + WS_WSF);
  int*   route= (int*)(ws + WS_ROUTE);
  int*   grp  = (int*)(ws + WS_GRP);
  f16*   x16  = (f16*)(ws + WS_X16);
  f16*   w1t  = (f16*)(ws + WS_W1T);
  f16*   w2t  = (f16*)(ws + WS_W2T);
  f16*   h1   = (f16*)(ws + WS_H1);

  gate_kernel<<<Bn, 64, 0, stream>>>(x, Wg, out, wsf, route);
  group_kernel<<<1, 64, 0, stream>>>(route, grp);
  loss_kernel<<<1, 64, 0, stream>>>(wsf, out);
  convx_kernel<<<1536, 256, 0, stream>>>(x, x16);
  transcvt_kernel<<<dim3(48,12,4), 256, 0, stream>>>(W1, w1t, Hn, Fn);
  transcvt_kernel<<<dim3(12,48,4), 256, 0, stream>>>(W2, w2t, Fn, Hn);

  auto g1 = gemm_kernel<Hn, Fn, 256, 4, true>;
  auto g2 = gemm_kernel<Fn, Hn, 128, 2, false>;
  const int smB = 131072;
  hipFuncSetAttribute((const void*)g1, hipFuncAttributeMaxDynamicSharedMemorySize, smB);
  hipFuncSetAttribute((const void*)g2, hipFuncAttributeMaxDynamicSharedMemorySize, smB);
  g1<<<35*12, 1024, smB, stream>>>(x16, w1t, b1, h1, nullptr, grp, wsf);
  g2<<<35*6,  1024, smB, stream>>>(h1, w2t, b2, nullptr, out, grp, wsf);
}